// Round 7
// baseline (919.636 us; speedup 1.0000x reference)
//
#include <hip/hip_runtime.h>

constexpr int NN = 50000;
constexpr int NE = 1600000;
constexpr int NG = 1000;
constexpr int STRIDE = 64;            // padded-CSR row capacity (deg ~Poisson(32), P(>64)~5e-9)

// workspace layout in 4-byte units
constexpr int OFF_CURS  = 0;          // int[50048]      (zeroed)
constexpr int OFF_AGGR1 = 50048;      // f32[NN*8]       (zeroed)
constexpr int OFF_SUMS  = 450048;     // f32[64000]      (zeroed)
constexpr int OFF_CNT   = 514048;     // f32[1024]       (zeroed)
constexpr int ZERO_UNITS= 515072;
constexpr int OFF_EAB   = 515072;     // uint2[NE]   = 3200000 units (8B aligned)
constexpr int OFF_SE2   = 3715072;    // int2[NN*64] = 6400000 units (8B aligned)
constexpr int OFF_H1    = 10115072;   // bf16[NN*64] = 1600000 units
constexpr int OFF_Z     = 11715072;   // packed bf16 uint[NN*32] = 1600000 units
// end = 13,315,072 units = 53.3 MB

__device__ __forceinline__ unsigned int f2bf(float f) {   // RNE fp32->bf16 bits
    unsigned int u = __float_as_uint(f);
    return (u + 0x7fffu + ((u >> 16) & 1u)) >> 16;
}
__device__ __forceinline__ float bf2f_lo(unsigned int p) { return __uint_as_float(p << 16); }
__device__ __forceinline__ float bf2f_hi(unsigned int p) { return __uint_as_float(p & 0xffff0000u); }

// ---------- fused: padded-CSR scatter + edge_attr bf16 pack + layer-1 edge aggregation ----------
__global__ __launch_bounds__(256) void escatter_kernel(
    const int* __restrict__ eidx, const float4* __restrict__ ea,
    const float* __restrict__ x,
    const float* __restrict__ We1, const float* __restrict__ be1,
    int* __restrict__ cursor, int2* __restrict__ se2,
    uint2* __restrict__ eab, float* __restrict__ aggr1)
{
    float w[4][7], b[7];                 // wave-uniform -> scalar regs
    #pragma unroll
    for (int k = 0; k < 4; ++k)
        #pragma unroll
        for (int d = 0; d < 7; ++d) w[k][d] = We1[k * 7 + d];
    #pragma unroll
    for (int d = 0; d < 7; ++d) b[d] = be1[d];

    int tid = blockIdx.x * 256 + threadIdx.x;
    int stride = gridDim.x * 256;
    for (int e = tid; e < NE; e += stride) {
        int src = eidx[e];
        int dst = eidx[NE + e];
        float4 a = ea[e];
        eab[e] = make_uint2(f2bf(a.x) | (f2bf(a.y) << 16),
                            f2bf(a.z) | (f2bf(a.w) << 16));   // sequential, coalesced
        int pos = atomicAdd(&cursor[dst], 1);
        if (pos < STRIDE) se2[((size_t)dst << 6) + pos] = make_int2(src, e);
        const float* xs = x + (size_t)src * 7;
        float* ag = aggr1 + ((size_t)dst << 3);
        #pragma unroll
        for (int d = 0; d < 7; ++d) {                          // fire-and-forget fp32 atomics
            float m = b[d] + a.x * w[0][d] + a.y * w[1][d]
                    + a.z * w[2][d] + a.w * w[3][d] + xs[d];
            atomicAdd(ag + d, fmaxf(m, 0.f));
        }
    }
}

// ---------- node-1 MLP: h1 = relu(relu((x+aggr1)@W1a+b1a)@W1b+b1b), bf16 out ----------
__global__ __launch_bounds__(256) void node1_kernel(
    const float* __restrict__ x, const float* __restrict__ aggr1,
    const float* __restrict__ W1a, const float* __restrict__ b1a,
    const float* __restrict__ W1b, const float* __restrict__ b1b,
    unsigned short* __restrict__ h1)
{
    __shared__ float sWa[7 * 64];
    __shared__ float sWb[64 * 64];
    __shared__ float sba[64], sbb[64];
    __shared__ float tbuf[4][64];
    int t = threadIdx.x;
    for (int i = t; i < 7 * 64; i += 256) sWa[i] = W1a[i];
    for (int i = t; i < 64 * 64; i += 256) sWb[i] = W1b[i];
    if (t < 64) { sba[t] = b1a[t]; sbb[t] = b1b[t]; }
    __syncthreads();
    const int w = t >> 6, lane = t & 63;
    for (int n = blockIdx.x * 4 + w; n < NN; n += gridDim.x * 4) {
        float zl = (lane < 7) ? (x[(size_t)n * 7 + lane] + aggr1[((size_t)n << 3) + lane]) : 0.f;
        float tt = sba[lane];
        #pragma unroll
        for (int k = 0; k < 7; ++k) tt += __shfl(zl, k) * sWa[k * 64 + lane];
        tt = fmaxf(tt, 0.f);
        tbuf[w][lane] = tt;              // wave64 lockstep, no barrier
        float o = sbb[lane];
        #pragma unroll 8
        for (int k = 0; k < 64; ++k) o += tbuf[w][k] * sWb[k * 64 + lane];
        h1[(size_t)n * 64 + lane] = (unsigned short)f2bf(fmaxf(o, 0.f));
    }
}

// ---------- Layer 2 aggregation: 2 dims/lane, 16 edges (8 dword gathers) in flight ----------
__global__ __launch_bounds__(256) void aggr2_kernel(
    const unsigned int* __restrict__ h1u, const int2* __restrict__ se2,
    const uint2* __restrict__ eab, const int* __restrict__ cursor,
    const float* __restrict__ We2, const float* __restrict__ be2,
    unsigned int* __restrict__ zb)
{
    __shared__ float sWe[256];
    __shared__ float sbe[64];
    int tid = threadIdx.x;
    sWe[tid] = We2[tid];
    if (tid < 64) sbe[tid] = be2[tid];
    __syncthreads();
    const int w = tid >> 6, lane = tid & 63;
    const int l = lane & 31;
    const int half8 = (lane >> 5) << 3;            // 0 or 8
    const int n = blockIdx.x * 4 + w;
    const size_t off = (size_t)n << 6;
    int deg = cursor[n]; if (deg > STRIDE) deg = STRIDE;
    // per-lane weights for dims (2l, 2l+1)
    const float w0x = sWe[2 * l],       w0y = sWe[2 * l + 1];
    const float w1x = sWe[64 + 2 * l],  w1y = sWe[64 + 2 * l + 1];
    const float w2x = sWe[128 + 2 * l], w2y = sWe[128 + 2 * l + 1];
    const float w3x = sWe[192 + 2 * l], w3y = sWe[192 + 2 * l + 1];
    const float bbx = sbe[2 * l],       bby = sbe[2 * l + 1];

    float accx = 0.f, accy = 0.f;
    for (int jb = 0; jb < deg; jb += 16) {
        int m = deg - jb;                           // wave-uniform
        int ll = (lane < 16) ? ((lane < m) ? lane : 0) : 0;
        int2 q = se2[off + jb + ll];                // lanes 0..15: {src, eid}
        uint2 ev = eab[(lane < 16) ? (size_t)q.y : 0];   // lanes 0..15: packed edge_attr
        unsigned int g[8];
        #pragma unroll
        for (int k = 0; k < 8; ++k) {               // 8 independent gathers in flight
            int mk = k + half8;
            int sk = __shfl(q.x, (mk < m) ? mk : 0);
            g[k] = h1u[(size_t)sk * 32 + l];
        }
        #pragma unroll
        for (int k = 0; k < 8; ++k) {
            int mk = k + half8;
            int sl = (mk < m) ? mk : 0;
            unsigned int py = (unsigned int)__shfl((int)ev.x, sl);
            unsigned int pz = (unsigned int)__shfl((int)ev.y, sl);
            float e0 = bf2f_lo(py), e1 = bf2f_hi(py);
            float e2 = bf2f_lo(pz), e3 = bf2f_hi(pz);
            float bx = bbx + e0 * w0x + e1 * w1x + e2 * w2x + e3 * w3x;
            float by = bby + e0 * w0y + e1 * w1y + e2 * w2y + e3 * w3y;
            float tx = fmaxf(bf2f_lo(g[k]) + bx, 0.f);
            float ty = fmaxf(bf2f_hi(g[k]) + by, 0.f);
            if (mk < m) { accx += tx; accy += ty; }
        }
    }
    accx += __shfl_xor(accx, 32);                   // merge the two half-wave edge sets
    accy += __shfl_xor(accy, 32);
    if (lane < 32) {
        unsigned int sw = h1u[(size_t)n * 32 + l];
        float zx = bf2f_lo(sw) + accx;
        float zy = bf2f_hi(sw) + accy;
        zb[(size_t)n * 32 + l] = f2bf(zx) | (f2bf(zy) << 16);
    }
}

// ---------- Layer 2 MLP + fused global-mean-pool (z packed bf16) ----------
__global__ __launch_bounds__(256) void mlp2_kernel(
    const unsigned int* __restrict__ zb,
    const float* __restrict__ W2a, const float* __restrict__ b2a,
    const float* __restrict__ W2b, const float* __restrict__ b2b,
    const int* __restrict__ batch,
    float* __restrict__ sums, float* __restrict__ cnt)
{
    __shared__ float sWa[64 * 64];
    __shared__ float sWb[64 * 64];
    __shared__ float sba[64], sbb[64];
    __shared__ float zbuf[4][64];
    __shared__ float tbuf[4][64];
    int t = threadIdx.x;
    for (int i = t; i < 64 * 64; i += 256) { sWa[i] = W2a[i]; sWb[i] = W2b[i]; }
    if (t < 64) { sba[t] = b2a[t]; sbb[t] = b2b[t]; }
    __syncthreads();
    const int w = t >> 6, lane = t & 63;
    const int l = lane & 31, h = lane >> 5;
    for (int n = blockIdx.x * 4 + w; n < NN; n += gridDim.x * 4) {
        unsigned int zw = zb[(size_t)n * 32 + l];
        zbuf[w][2 * l + h] = h ? bf2f_hi(zw) : bf2f_lo(zw);
        float tt = sba[lane];
        #pragma unroll 8
        for (int k = 0; k < 64; ++k) tt += zbuf[w][k] * sWa[k * 64 + lane];
        tt = fmaxf(tt, 0.f);
        tbuf[w][lane] = tt;
        float o = sbb[lane];
        #pragma unroll 8
        for (int k = 0; k < 64; ++k) o += tbuf[w][k] * sWb[k * 64 + lane];
        o = fmaxf(o, 0.f);
        int g = batch[n];
        atomicAdd(sums + (size_t)g * 64 + lane, o);
        if (lane == 0) atomicAdd(cnt + g, 1.0f);
    }
}

// ---------- FC ----------
__global__ __launch_bounds__(256) void fc_kernel(
    const float* __restrict__ sums, const float* __restrict__ cnt,
    const float* __restrict__ Wfc, const float* __restrict__ bfc,
    float* __restrict__ out)
{
    int gid = blockIdx.x * blockDim.x + threadIdx.x;
    if (gid >= NG * 12) return;
    int g = gid / 12, jj = gid - g * 12;
    float inv = 1.f / fmaxf(cnt[g], 1.f);
    float acc = bfc[jj];
    #pragma unroll 8
    for (int k = 0; k < 64; ++k) acc += sums[(size_t)g * 64 + k] * inv * Wfc[k * 12 + jj];
    out[gid] = acc;
}

extern "C" void kernel_launch(void* const* d_in, const int* in_sizes, int n_in,
                              void* d_out, int out_size, void* d_ws, size_t ws_size,
                              hipStream_t stream)
{
    (void)in_sizes; (void)n_in; (void)out_size; (void)ws_size;
    const float*  x    = (const float*)d_in[0];
    const float4* ea   = (const float4*)d_in[1];
    const int*    eidx = (const int*)d_in[2];
    const int*    batch= (const int*)d_in[3];
    const float*  We1  = (const float*)d_in[4];
    const float*  be1  = (const float*)d_in[5];
    const float*  W1a  = (const float*)d_in[6];
    const float*  b1a  = (const float*)d_in[7];
    const float*  W1b  = (const float*)d_in[8];
    const float*  b1b  = (const float*)d_in[9];
    const float*  We2  = (const float*)d_in[10];
    const float*  be2  = (const float*)d_in[11];
    const float*  W2a  = (const float*)d_in[12];
    const float*  b2a  = (const float*)d_in[13];
    const float*  W2b  = (const float*)d_in[14];
    const float*  b2b  = (const float*)d_in[15];
    const float*  Wfc  = (const float*)d_in[16];
    const float*  bfc  = (const float*)d_in[17];
    float* out = (float*)d_out;
    float* ws  = (float*)d_ws;

    int*            cursor = (int*)(ws + OFF_CURS);
    float*          aggr1  = ws + OFF_AGGR1;
    float*          sums   = ws + OFF_SUMS;
    float*          cnt    = ws + OFF_CNT;
    uint2*          eab    = (uint2*)(ws + OFF_EAB);
    int2*           se2    = (int2*)(ws + OFF_SE2);
    unsigned short* h1     = (unsigned short*)(ws + OFF_H1);
    unsigned int*   h1u    = (unsigned int*)(ws + OFF_H1);
    unsigned int*   zb     = (unsigned int*)(ws + OFF_Z);

    hipMemsetAsync(d_ws, 0, (size_t)ZERO_UNITS * 4, stream);

    escatter_kernel<<<2048, 256, 0, stream>>>(eidx, ea, x, We1, be1, cursor, se2, eab, aggr1);
    node1_kernel   <<<850, 256, 0, stream>>>(x, aggr1, W1a, b1a, W1b, b1b, h1);
    aggr2_kernel   <<<12500, 256, 0, stream>>>(h1u, se2, eab, cursor, We2, be2, zb);
    mlp2_kernel    <<<850, 256, 0, stream>>>(zb, W2a, b2a, W2b, b2b, batch, sums, cnt);
    fc_kernel      <<<(NG * 12 + 255) / 256, 256, 0, stream>>>(sums, cnt, Wfc, bfc, out);
}

// Round 8
// 443.515 us; speedup vs baseline: 2.0735x; 2.0735x over previous
//
#include <hip/hip_runtime.h>

constexpr int NN = 50000;
constexpr int NE = 1600000;
constexpr int NG = 1000;
constexpr int NBLK = 196;            // scan blocks: 196*256 = 50176 >= NN
constexpr int NPART = 8;             // XCD count; dst-space partitions
constexpr int PSZ = (NN + NPART - 1) / NPART;   // 6250 nodes per partition

// workspace layout in 4-byte units
constexpr int OFF_DEG   = 0;          // int[50176]  (zeroed)
constexpr int OFF_SUMS  = 50176;      // f32[64000]  (zeroed)
constexpr int OFF_CNT   = 114176;     // f32[1024]   (zeroed)
constexpr int ZERO_UNITS= 115200;
constexpr int OFF_OFFS  = 115200;     // int[50176]
constexpr int OFF_CURS  = 165376;     // int[50176]
constexpr int OFF_BTOT  = 215552;     // int[256]
constexpr int OFF_BEXCL = 215808;     // int[256]
constexpr int OFF_SE4   = 216064;     // int4[NE] = 6400000 units (16B aligned)
constexpr int OFF_H1    = 6616064;    // bf16[NN*64] = 1600000 units
constexpr int OFF_Z     = 8216064;    // bf16[NN*64] = 1600000 units (packed 2/uint)
// end = 9,816,064 units = 39.3 MB

__device__ __forceinline__ unsigned int f2bf(float f) {   // RNE fp32->bf16 bits
    unsigned int u = __float_as_uint(f);
    return (u + 0x7fffu + ((u >> 16) & 1u)) >> 16;
}
__device__ __forceinline__ float bf2f_lo(unsigned int p) { return __uint_as_float(p << 16); }
__device__ __forceinline__ float bf2f_hi(unsigned int p) { return __uint_as_float(p & 0xffff0000u); }

// ---------- degree histogram ----------
__global__ __launch_bounds__(256) void hist_kernel(const int* __restrict__ eidx,
                                                   int* __restrict__ deg) {
    int tid = blockIdx.x * 256 + threadIdx.x;
    int stride = gridDim.x * 256;
    for (int e = tid; e < NE; e += stride) atomicAdd(&deg[eidx[NE + e]], 1);
}

__global__ __launch_bounds__(256) void scanA_kernel(const int* __restrict__ deg,
                                                    int* __restrict__ offs,
                                                    int* __restrict__ btot) {
    __shared__ int s[256];
    int t = threadIdx.x;
    int i = blockIdx.x * 256 + t;
    int v = (i < NN) ? deg[i] : 0;
    s[t] = v; __syncthreads();
    for (int o = 1; o < 256; o <<= 1) {
        int u = (t >= o) ? s[t - o] : 0;
        __syncthreads();
        s[t] += u;
        __syncthreads();
    }
    offs[i] = s[t] - v;
    if (t == 255) btot[blockIdx.x] = s[255];
}

__global__ __launch_bounds__(256) void scanB_kernel(const int* __restrict__ btot,
                                                    int* __restrict__ bexcl) {
    __shared__ int s[256];
    int t = threadIdx.x;
    int v = (t < NBLK) ? btot[t] : 0;
    s[t] = v; __syncthreads();
    for (int o = 1; o < 256; o <<= 1) {
        int u = (t >= o) ? s[t - o] : 0;
        __syncthreads();
        s[t] += u;
        __syncthreads();
    }
    bexcl[t] = s[t] - v;
}

__global__ __launch_bounds__(256) void scanC_kernel(int* __restrict__ offs,
                                                    const int* __restrict__ bexcl,
                                                    int* __restrict__ cursor) {
    int i = blockIdx.x * 256 + threadIdx.x;
    int o = offs[i] + bexcl[blockIdx.x];
    offs[i] = o;
    cursor[i] = o;
}

// ---------- XCD-partitioned scatter into CSR ----------
// blocks with blockIdx&7==p process only dst in [p*PSZ,(p+1)*PSZ): all records of a
// 64B CSR line funnel through one XCD's L2 (3.2MB slice < 4MB) and assemble before
// writeback. If blockIdx->XCD isn't round-robin this is merely neutral.
__global__ __launch_bounds__(256) void scatter_kernel(const int* __restrict__ eidx,
                                                      const float4* __restrict__ ea,
                                                      int* __restrict__ cursor,
                                                      int4* __restrict__ se4) {
    const int part = blockIdx.x & (NPART - 1);
    const int lo = part * PSZ, hi = lo + PSZ;
    const int gb = blockIdx.x >> 3;                 // 0..255 within group
    const int tid = gb * 256 + threadIdx.x;
    const int stride = (gridDim.x >> 3) * 256;
    for (int e = tid; e < NE; e += stride) {
        int dst = eidx[NE + e];
        if (dst < lo || dst >= hi) continue;
        int src = eidx[e];
        float4 a = ea[e];
        int4 p;
        p.x = src;
        p.y = (int)(f2bf(a.x) | (f2bf(a.y) << 16));
        p.z = (int)(f2bf(a.z) | (f2bf(a.w) << 16));
        p.w = 0;
        int pos = atomicAdd(&cursor[dst], 1);
        se4[pos] = p;
    }
}

// ---------- Layer 1 fused: aggregate (8 edges x 8 dims, 2 batches in flight) + MLP ----------
// grid-strided: LDS weight fill amortized over ~20 nodes/block
__global__ __launch_bounds__(256) void layer1_kernel(
    const float* __restrict__ x, const int4* __restrict__ se4,
    const int* __restrict__ offs,
    const float* __restrict__ We1, const float* __restrict__ be1,
    const float* __restrict__ W1a, const float* __restrict__ b1a,
    const float* __restrict__ W1b, const float* __restrict__ b1b,
    unsigned short* __restrict__ h1)
{
    __shared__ float sWe[32];          // [k_in 0..3][d_out 0..7], col 7 zeroed
    __shared__ float sbe[8];
    __shared__ float sWa[7 * 64];
    __shared__ float sWb[64 * 64];
    __shared__ float sba[64], sbb[64];
    __shared__ float tbuf[4][64];
    int tid = threadIdx.x;
    if (tid < 32) { int k = tid >> 3, dd = tid & 7; sWe[tid] = (dd < 7) ? We1[k * 7 + dd] : 0.f; }
    if (tid < 8)  sbe[tid] = (tid < 7) ? be1[tid] : 0.f;
    for (int i = tid; i < 7 * 64; i += 256) sWa[i] = W1a[i];
    for (int i = tid; i < 64 * 64; i += 256) sWb[i] = W1b[i];
    if (tid < 64) { sba[tid] = b1a[tid]; sbb[tid] = b1b[tid]; }
    __syncthreads();

    const int w = tid >> 6, lane = tid & 63;
    const int jg = lane >> 3, d = lane & 7;

    for (int n = blockIdx.x * 4 + w; n < NN; n += gridDim.x * 4) {
        const int off = offs[n];
        const int deg = offs[n + 1] - off;

        float acc = 0.f;
        for (int j0 = 0; j0 < deg; j0 += 16) {
            int ja = j0 + jg;
            int jb = j0 + 8 + jg;
            int4 pa = se4[off + ((ja < deg) ? ja : 0)];     // two independent chains
            int4 pb = se4[off + ((jb < deg) ? jb : 0)];
            float xa = (d < 7) ? x[(size_t)pa.x * 7 + d] : 0.f;
            float xb = (d < 7) ? x[(size_t)pb.x * 7 + d] : 0.f;
            float va = sbe[d] + bf2f_lo((unsigned)pa.y) * sWe[d] + bf2f_hi((unsigned)pa.y) * sWe[8 + d]
                     + bf2f_lo((unsigned)pa.z) * sWe[16 + d] + bf2f_hi((unsigned)pa.z) * sWe[24 + d] + xa;
            float vb = sbe[d] + bf2f_lo((unsigned)pb.y) * sWe[d] + bf2f_hi((unsigned)pb.y) * sWe[8 + d]
                     + bf2f_lo((unsigned)pb.z) * sWe[16 + d] + bf2f_hi((unsigned)pb.z) * sWe[24 + d] + xb;
            va = (d < 7 && ja < deg) ? fmaxf(va, 0.f) : 0.f;
            vb = (d < 7 && jb < deg) ? fmaxf(vb, 0.f) : 0.f;
            acc += va + vb;
        }
        acc += __shfl_xor(acc, 8);
        acc += __shfl_xor(acc, 16);
        acc += __shfl_xor(acc, 32);
        float zl = ((d < 7) ? x[(size_t)n * 7 + d] : 0.f) + acc;

        float t = sba[lane];
        #pragma unroll
        for (int k = 0; k < 7; ++k) t += __shfl(zl, k) * sWa[k * 64 + lane];
        t = fmaxf(t, 0.f);
        tbuf[w][lane] = t;             // wave64 lockstep, no barrier
        float o = sbb[lane];
        #pragma unroll 8
        for (int k = 0; k < 64; ++k) o += tbuf[w][k] * sWb[k * 64 + lane];
        h1[(size_t)n * 64 + lane] = (unsigned short)f2bf(fmaxf(o, 0.f));
    }
}

// ---------- Layer 2 aggregation: 2 dims/lane, 16 edges (8 dword gathers) in flight ----------
__global__ __launch_bounds__(256) void aggr2_kernel(
    const unsigned int* __restrict__ h1u, const int4* __restrict__ se4,
    const int* __restrict__ offs,
    const float* __restrict__ We2, const float* __restrict__ be2,
    unsigned int* __restrict__ zb)
{
    __shared__ float sWe[256];
    __shared__ float sbe[64];
    int tid = threadIdx.x;
    sWe[tid] = We2[tid];
    if (tid < 64) sbe[tid] = be2[tid];
    __syncthreads();
    const int w = tid >> 6, lane = tid & 63;
    const int l = lane & 31;
    const int half8 = (lane >> 5) << 3;            // 0 or 8
    const int n = blockIdx.x * 4 + w;
    const int off = offs[n];
    const int deg = offs[n + 1] - off;
    // per-lane weights for dims (2l, 2l+1)
    const float w0x = sWe[2 * l],       w0y = sWe[2 * l + 1];
    const float w1x = sWe[64 + 2 * l],  w1y = sWe[64 + 2 * l + 1];
    const float w2x = sWe[128 + 2 * l], w2y = sWe[128 + 2 * l + 1];
    const float w3x = sWe[192 + 2 * l], w3y = sWe[192 + 2 * l + 1];
    const float bbx = sbe[2 * l],       bby = sbe[2 * l + 1];

    float accx = 0.f, accy = 0.f;
    for (int jb = 0; jb < deg; jb += 16) {
        int m = deg - jb;                           // wave-uniform
        int ll = (lane < 16) ? ((lane < m) ? lane : 0) : 0;
        int4 p = se4[off + jb + ll];                // lanes 0..15 hold 16 edges
        unsigned int g[8];
        #pragma unroll
        for (int k = 0; k < 8; ++k) {               // 8 independent gathers in flight
            int mk = k + half8;
            int sk = __shfl(p.x, (mk < m) ? mk : 0);
            g[k] = h1u[(size_t)sk * 32 + l];
        }
        #pragma unroll
        for (int k = 0; k < 8; ++k) {
            int mk = k + half8;
            int sl = (mk < m) ? mk : 0;
            unsigned int py = (unsigned int)__shfl(p.y, sl);
            unsigned int pz = (unsigned int)__shfl(p.z, sl);
            float e0 = bf2f_lo(py), e1 = bf2f_hi(py);
            float e2 = bf2f_lo(pz), e3 = bf2f_hi(pz);
            float bx = bbx + e0 * w0x + e1 * w1x + e2 * w2x + e3 * w3x;
            float by = bby + e0 * w0y + e1 * w1y + e2 * w2y + e3 * w3y;
            float tx = fmaxf(bf2f_lo(g[k]) + bx, 0.f);
            float ty = fmaxf(bf2f_hi(g[k]) + by, 0.f);
            if (mk < m) { accx += tx; accy += ty; }
        }
    }
    accx += __shfl_xor(accx, 32);                   // merge the two half-wave edge sets
    accy += __shfl_xor(accy, 32);
    if (lane < 32) {
        unsigned int sw = h1u[(size_t)n * 32 + l];
        float zx = bf2f_lo(sw) + accx;
        float zy = bf2f_hi(sw) + accy;
        zb[(size_t)n * 32 + l] = f2bf(zx) | (f2bf(zy) << 16);
    }
}

// ---------- Layer 2 MLP + fused global-mean-pool (z packed bf16) ----------
__global__ __launch_bounds__(256) void mlp2_kernel(
    const unsigned int* __restrict__ zb,
    const float* __restrict__ W2a, const float* __restrict__ b2a,
    const float* __restrict__ W2b, const float* __restrict__ b2b,
    const int* __restrict__ batch,
    float* __restrict__ sums, float* __restrict__ cnt)
{
    __shared__ float sWa[64 * 64];
    __shared__ float sWb[64 * 64];
    __shared__ float sba[64], sbb[64];
    __shared__ float zbuf[4][64];
    __shared__ float tbuf[4][64];
    int t = threadIdx.x;
    for (int i = t; i < 64 * 64; i += 256) { sWa[i] = W2a[i]; sWb[i] = W2b[i]; }
    if (t < 64) { sba[t] = b2a[t]; sbb[t] = b2b[t]; }
    __syncthreads();
    const int w = t >> 6, lane = t & 63;
    const int l = lane & 31, h = lane >> 5;
    for (int n = blockIdx.x * 4 + w; n < NN; n += gridDim.x * 4) {
        unsigned int zw = zb[(size_t)n * 32 + l];
        zbuf[w][2 * l + h] = h ? bf2f_hi(zw) : bf2f_lo(zw);
        float tt = sba[lane];
        #pragma unroll 8
        for (int k = 0; k < 64; ++k) tt += zbuf[w][k] * sWa[k * 64 + lane];
        tt = fmaxf(tt, 0.f);
        tbuf[w][lane] = tt;
        float o = sbb[lane];
        #pragma unroll 8
        for (int k = 0; k < 64; ++k) o += tbuf[w][k] * sWb[k * 64 + lane];
        o = fmaxf(o, 0.f);
        int g = batch[n];
        atomicAdd(sums + (size_t)g * 64 + lane, o);
        if (lane == 0) atomicAdd(cnt + g, 1.0f);
    }
}

// ---------- FC ----------
__global__ __launch_bounds__(256) void fc_kernel(
    const float* __restrict__ sums, const float* __restrict__ cnt,
    const float* __restrict__ Wfc, const float* __restrict__ bfc,
    float* __restrict__ out)
{
    int gid = blockIdx.x * blockDim.x + threadIdx.x;
    if (gid >= NG * 12) return;
    int g = gid / 12, jj = gid - g * 12;
    float inv = 1.f / fmaxf(cnt[g], 1.f);
    float acc = bfc[jj];
    #pragma unroll 8
    for (int k = 0; k < 64; ++k) acc += sums[(size_t)g * 64 + k] * inv * Wfc[k * 12 + jj];
    out[gid] = acc;
}

extern "C" void kernel_launch(void* const* d_in, const int* in_sizes, int n_in,
                              void* d_out, int out_size, void* d_ws, size_t ws_size,
                              hipStream_t stream)
{
    (void)in_sizes; (void)n_in; (void)out_size; (void)ws_size;
    const float*  x    = (const float*)d_in[0];
    const float4* ea   = (const float4*)d_in[1];
    const int*    eidx = (const int*)d_in[2];
    const int*    batch= (const int*)d_in[3];
    const float*  We1  = (const float*)d_in[4];
    const float*  be1  = (const float*)d_in[5];
    const float*  W1a  = (const float*)d_in[6];
    const float*  b1a  = (const float*)d_in[7];
    const float*  W1b  = (const float*)d_in[8];
    const float*  b1b  = (const float*)d_in[9];
    const float*  We2  = (const float*)d_in[10];
    const float*  be2  = (const float*)d_in[11];
    const float*  W2a  = (const float*)d_in[12];
    const float*  b2a  = (const float*)d_in[13];
    const float*  W2b  = (const float*)d_in[14];
    const float*  b2b  = (const float*)d_in[15];
    const float*  Wfc  = (const float*)d_in[16];
    const float*  bfc  = (const float*)d_in[17];
    float* out = (float*)d_out;
    float* ws  = (float*)d_ws;

    int*            deg    = (int*)(ws + OFF_DEG);
    float*          sums   = ws + OFF_SUMS;
    float*          cnt    = ws + OFF_CNT;
    int*            offs   = (int*)(ws + OFF_OFFS);
    int*            cursor = (int*)(ws + OFF_CURS);
    int*            btot   = (int*)(ws + OFF_BTOT);
    int*            bexcl  = (int*)(ws + OFF_BEXCL);
    int4*           se4    = (int4*)(ws + OFF_SE4);
    unsigned short* h1     = (unsigned short*)(ws + OFF_H1);
    unsigned int*   h1u    = (unsigned int*)(ws + OFF_H1);
    unsigned int*   zb     = (unsigned int*)(ws + OFF_Z);

    hipMemsetAsync(d_ws, 0, (size_t)ZERO_UNITS * 4, stream);

    hist_kernel   <<<1024, 256, 0, stream>>>(eidx, deg);
    scanA_kernel  <<<NBLK, 256, 0, stream>>>(deg, offs, btot);
    scanB_kernel  <<<1,    256, 0, stream>>>(btot, bexcl);
    scanC_kernel  <<<NBLK, 256, 0, stream>>>(offs, bexcl, cursor);
    scatter_kernel<<<2048, 256, 0, stream>>>(eidx, ea, cursor, se4);
    layer1_kernel <<<2500, 256, 0, stream>>>(x, se4, offs, We1, be1, W1a, b1a, W1b, b1b, h1);
    aggr2_kernel  <<<12500, 256, 0, stream>>>(h1u, se4, offs, We2, be2, zb);
    mlp2_kernel   <<<850, 256, 0, stream>>>(zb, W2a, b2a, W2b, b2b, batch, sums, cnt);
    fc_kernel     <<<(NG * 12 + 255) / 256, 256, 0, stream>>>(sums, cnt, Wfc, bfc, out);
}